// Round 1
// baseline (231.310 us; speedup 1.0000x reference)
//
#include <hip/hip_runtime.h>
#include <hip/hip_bf16.h>
#include <math.h>

// Problem dims (fixed by the reference): B=4096, M=2, D=2048
#define MROWS 8192   // B*M rows of the GEMM
#define KDIM  2048
#define NDIM  2048

#define BM 256
#define BN 256
#define BK 64
#define NT (KDIM / BK)   // 32 K-tiles

typedef short  v8s __attribute__((ext_vector_type(8)));   // 8 bf16 (4 VGPRs)
typedef float  v4f __attribute__((ext_vector_type(4)));   // MFMA acc

// workspace layout (bytes)
#define A_OFF   0ull
#define W_OFF   ((unsigned long long)MROWS * KDIM * 2ull)               // 32 MiB
#define MWZ_OFF (W_OFF + (unsigned long long)NDIM * KDIM * 2ull)        // +8 MiB

__device__ inline unsigned short f2bf(float f) {
    __hip_bfloat16 h = __float2bfloat16(f);   // RNE
    return *reinterpret_cast<unsigned short*>(&h);
}

// ---------------------------------------------------------------------------
// Prep: zeta scalar, A = bf16(x + emb[ids]), W = bf16(Wt)   [UNCHANGED]
// ---------------------------------------------------------------------------
__global__ __launch_bounds__(256) void prep_kernel(
    const float* __restrict__ x, const int* __restrict__ ids,
    const float* __restrict__ mw, const float* __restrict__ emb,
    const float* __restrict__ Wrc, const float* __restrict__ brc,
    const float* __restrict__ Wt,
    unsigned short* __restrict__ Abf, unsigned short* __restrict__ Wbf,
    float* __restrict__ mwz)
{
    const int tid = threadIdx.x;

    if (blockIdx.x == 0) {
        __shared__ float red[256];
        float s = 0.f;
        for (int d = tid; d < KDIM; d += 256) s += Wrc[d];
        red[tid] = s;
        __syncthreads();
        for (int off = 128; off > 0; off >>= 1) {
            if (tid < off) red[tid] += red[tid + off];
            __syncthreads();
        }
        if (tid == 0) {
            float zeta = 1.0f / (1.0f + expf(-(0.2f * red[0] + brc[0])));
            mwz[0] = mw[0] * zeta;
            mwz[1] = mw[1] * zeta;
        }
    }

    const int groupsA = MROWS * KDIM / 8;
    for (int g = blockIdx.x * 256 + tid; g < groupsA; g += gridDim.x * 256) {
        const int row = g >> 8;
        const int off = (g & 255) << 3;
        const int st  = ids[row];
        const float4* xp = (const float4*)(x   + (size_t)row * KDIM + off);
        const float4* ep = (const float4*)(emb + (size_t)st  * KDIM + off);
        float4 x0 = xp[0], x1 = xp[1];
        float4 e0 = ep[0], e1 = ep[1];
        v8s o;
        o[0] = (short)f2bf(x0.x + e0.x);
        o[1] = (short)f2bf(x0.y + e0.y);
        o[2] = (short)f2bf(x0.z + e0.z);
        o[3] = (short)f2bf(x0.w + e0.w);
        o[4] = (short)f2bf(x1.x + e1.x);
        o[5] = (short)f2bf(x1.y + e1.y);
        o[6] = (short)f2bf(x1.z + e1.z);
        o[7] = (short)f2bf(x1.w + e1.w);
        *(v8s*)(Abf + (size_t)g * 8) = o;
    }

    const int groupsW = NDIM * KDIM / 8;
    for (int g = blockIdx.x * 256 + tid; g < groupsW; g += gridDim.x * 256) {
        const float4* wp = (const float4*)(Wt + (size_t)g * 8);
        float4 w0 = wp[0], w1 = wp[1];
        v8s o;
        o[0] = (short)f2bf(w0.x); o[1] = (short)f2bf(w0.y);
        o[2] = (short)f2bf(w0.z); o[3] = (short)f2bf(w0.w);
        o[4] = (short)f2bf(w1.x); o[5] = (short)f2bf(w1.y);
        o[6] = (short)f2bf(w1.z); o[7] = (short)f2bf(w1.w);
        *(v8s*)(Wbf + (size_t)g * 8) = o;
    }
}

// ---------------------------------------------------------------------------
// GEMM v2: 256x256 tile, 8 waves (2M x 4N), BK=64, double-buffered LDS,
// 4-phase/K-tile schedule with raw s_barrier + COUNTED vmcnt (T3+T4) and
// s_setprio around MFMA clusters (T5). Keeps the R3-verified fetch-side XOR
// swizzle (T2, measured 0 bank conflicts) and the operand-swap epilogue.
//
// Why this differs from the failed R4/R5 dbuf attempts: those used
// __syncthreads(), whose semantics force a vmcnt(0) drain at every barrier —
// prefetch cannot survive the barrier. Here waits are hand-counted so 8-12
// quarter-loads stay in flight across barriers; vmcnt never reaches 0 in the
// main loop.
//
// Region lifetimes per K-tile t (buf c = t&1), per-wave issue stream
// (2 global_load_lds calls per phase, 1 vmcnt unit each):
//   P0: read B(all)+A(rows 0-31 of wave)  | issue [t+1: A-q1,A-q3] -> c^1
//   P1: read A(rows 32-63)                | issue [t+2: B-q0,B-q1] -> c
//   P2: read A(rows 64-95)                | issue [t+2: B-q2,B-q3] -> c
//   P3: read A(rows 96-127)               | issue [t+2: A-q0,A-q2] -> c
// Waits (FIFO-counted): end-P1 vmcnt(10)  -> [t:A-q1,A-q3] landed (P2/P3 reads)
//                       end-P3 vmcnt(8)   -> [t+1: B*,A-q0,A-q2] landed (next P0/P1)
// lgkmcnt(0) before each closing barrier pins read-completion before any wave
// can issue an overwrite of that region (MFMAs may sink past asm barriers).
// Tail: stages wrap ((t+2)&31) into already-freed regions of the correct
// parity buffer, keeping vmcnt counts exact with no branches.
// ---------------------------------------------------------------------------

#define SBAR()   __builtin_amdgcn_s_barrier()
#define LGKM0()  asm volatile("s_waitcnt lgkmcnt(0)" ::: "memory")
#define VMCNT(n) asm volatile("s_waitcnt vmcnt(" #n ")" ::: "memory")

template<int P>
__device__ __forceinline__ void mfma_phase(v4f (&acc)[8][4],
                                           const v8s (&b)[4][2],
                                           const v8s (&a)[2][2])
{
    __builtin_amdgcn_s_setprio(1);
    #pragma unroll
    for (int j = 0; j < 4; ++j) {
        acc[2*P  ][j] = __builtin_amdgcn_mfma_f32_16x16x32_bf16(b[j][0], a[0][0], acc[2*P  ][j], 0, 0, 0);
        acc[2*P+1][j] = __builtin_amdgcn_mfma_f32_16x16x32_bf16(b[j][0], a[1][0], acc[2*P+1][j], 0, 0, 0);
    }
    #pragma unroll
    for (int j = 0; j < 4; ++j) {
        acc[2*P  ][j] = __builtin_amdgcn_mfma_f32_16x16x32_bf16(b[j][1], a[0][1], acc[2*P  ][j], 0, 0, 0);
        acc[2*P+1][j] = __builtin_amdgcn_mfma_f32_16x16x32_bf16(b[j][1], a[1][1], acc[2*P+1][j], 0, 0, 0);
    }
    __builtin_amdgcn_s_setprio(0);
}

__global__ __launch_bounds__(512, 2) void gemm_kernel(
    const unsigned short* __restrict__ Abf,
    const unsigned short* __restrict__ Wbf,
    const float* __restrict__ bt,
    const float* __restrict__ mwz,
    float* __restrict__ out)
{
    __shared__ __align__(16) unsigned short lA[2][BM * BK];   // 2 x 32 KiB
    __shared__ __align__(16) unsigned short lB[2][BN * BK];   // 2 x 32 KiB

    const int tid  = threadIdx.x;
    const int lane = tid & 63;
    const int wave = tid >> 6;        // 0..7
    const int wr   = wave & 1;        // M half (128 rows)
    const int wc   = wave >> 1;       // N quarter (64 cols)
    const int quad = lane >> 4;       // 0..3
    const int mcol = lane & 15;       // 0..15

    // T1: XCD-aware swizzle. 256 wgs = 8 XCDs x 32. Each XCD gets one bc
    // (one 1-MiB W panel, L2-resident) and streams all 32 br A-panels.
    const int flat = (int)blockIdx.x;
    const int wg   = ((flat & 7) << 5) | (flat >> 3);   // bijective, nwg%8==0
    const int br   = wg & 31;          // 32 row-blocks
    const int bc   = wg >> 5;          // 8 col-blocks

    const unsigned short* gA = Abf + (size_t)(br * BM) * KDIM;
    const unsigned short* gB = Wbf + (size_t)(bc * BN) * KDIM;

    v4f acc[8][4];
    const v4f vzero = {0.f, 0.f, 0.f, 0.f};
    #pragma unroll
    for (int i = 0; i < 8; i++)
        #pragma unroll
        for (int j = 0; j < 4; j++) acc[i][j] = vzero;

    // --- stage one 64-row quarter (8 KiB = 512 thr x 16 B) of a tile ---
    // LDS slot f holds row=f>>3, global chunk ch=(f&7)^(row&7)  (verified T2)
    auto stA = [&](int t, int s) {
        const int f   = (s << 9) + tid;
        const int row = f >> 3;
        const int ch  = (f & 7) ^ (row & 7);
        const unsigned short* g = gA + (size_t)row * KDIM + ((t & 31) << 6) + (ch << 3);
        __builtin_amdgcn_global_load_lds(
            (const __attribute__((address_space(1))) void*)g,
            (__attribute__((address_space(3))) void*)(&lA[t & 1][(size_t)f << 3]),
            16, 0, 0);
    };
    auto stB = [&](int t, int s) {
        const int f   = (s << 9) + tid;
        const int row = f >> 3;
        const int ch  = (f & 7) ^ (row & 7);
        const unsigned short* g = gB + (size_t)row * KDIM + ((t & 31) << 6) + (ch << 3);
        __builtin_amdgcn_global_load_lds(
            (const __attribute__((address_space(1))) void*)g,
            (__attribute__((address_space(3))) void*)(&lB[t & 1][(size_t)f << 3]),
            16, 0, 0);
    };

    // --- fragment reads (identical unswizzle math to verified R3 kernel) ---
    auto rdA = [&](const unsigned short* l, int i, int ks) -> v8s {
        const int row = (wr << 7) + (i << 4) + mcol;
        const int c   = ((ks << 2) + quad) ^ (row & 7);
        return *(const v8s*)(l + (row << 6) + (c << 3));
    };
    auto rdB = [&](const unsigned short* l, int j, int ks) -> v8s {
        const int col = (wc << 6) + (j << 4) + mcol;
        const int c   = ((ks << 2) + quad) ^ (col & 7);
        return *(const v8s*)(l + (col << 6) + (c << 3));
    };

    // ---- prologue: tile0 fully + tile1 {B*, A-q0,A-q2}; 14 calls in flight
    stB(0, 0); stB(0, 1); stB(0, 2); stB(0, 3);
    stA(0, 0); stA(0, 2);
    stA(0, 1); stA(0, 3);
    stB(1, 0); stB(1, 1); stB(1, 2); stB(1, 3);
    stA(1, 0); stA(1, 2);
    VMCNT(8);                 // oldest 6 = [t0: B*, A-q0,A-q2] landed
    SBAR();

    for (int t = 0; t < NT; ++t) {
        const unsigned short* cA = &lA[t & 1][0];
        const unsigned short* cB = &lB[t & 1][0];
        v8s a[2][2], b[4][2];

        // ---- P0 ----
        #pragma unroll
        for (int j = 0; j < 4; ++j) {
            b[j][0] = rdB(cB, j, 0);
            b[j][1] = rdB(cB, j, 1);
        }
        a[0][0] = rdA(cA, 0, 0); a[0][1] = rdA(cA, 0, 1);
        a[1][0] = rdA(cA, 1, 0); a[1][1] = rdA(cA, 1, 1);
        stA(t + 1, 1); stA(t + 1, 3);
        SBAR();
        mfma_phase<0>(acc, b, a);
        LGKM0(); SBAR();

        // ---- P1 ----
        a[0][0] = rdA(cA, 2, 0); a[0][1] = rdA(cA, 2, 1);
        a[1][0] = rdA(cA, 3, 0); a[1][1] = rdA(cA, 3, 1);
        stB(t + 2, 0); stB(t + 2, 1);
        SBAR();
        mfma_phase<1>(acc, b, a);
        LGKM0();
        VMCNT(10);            // [t: A-q1,A-q3] landed for P2/P3
        SBAR();

        // ---- P2 ----
        a[0][0] = rdA(cA, 4, 0); a[0][1] = rdA(cA, 4, 1);
        a[1][0] = rdA(cA, 5, 0); a[1][1] = rdA(cA, 5, 1);
        stB(t + 2, 2); stB(t + 2, 3);
        SBAR();
        mfma_phase<2>(acc, b, a);
        LGKM0(); SBAR();

        // ---- P3 ----
        a[0][0] = rdA(cA, 6, 0); a[0][1] = rdA(cA, 6, 1);
        a[1][0] = rdA(cA, 7, 0); a[1][1] = rdA(cA, 7, 1);
        stA(t + 2, 0); stA(t + 2, 2);
        SBAR();
        mfma_phase<3>(acc, b, a);
        LGKM0();
        VMCNT(8);             // [t+1: B*, A-q0,A-q2] landed for next P0/P1
        SBAR();
    }

    // ---- epilogue: bias + relu + scale + relu, dwordx4 fp32 stores ----
    // operand swap => acc holds out^T tile: reg-index = output COLUMN,
    // mcol = output ROW. Row parity = mcol & 1 (all tile offsets even).
    const float mz = mwz[mcol & 1];
    #pragma unroll
    for (int j = 0; j < 4; ++j) {
        const int ncol = bc * BN + wc * 64 + j * 16 + quad * 4;
        const float4 b4 = *(const float4*)(bt + ncol);
        #pragma unroll
        for (int i = 0; i < 8; ++i) {
            const int row = br * BM + wr * 128 + i * 16 + mcol;
            float4 o;
            o.x = fmaxf(mz * fmaxf(acc[i][j][0] + b4.x, 0.0f), 0.0f);
            o.y = fmaxf(mz * fmaxf(acc[i][j][1] + b4.y, 0.0f), 0.0f);
            o.z = fmaxf(mz * fmaxf(acc[i][j][2] + b4.z, 0.0f), 0.0f);
            o.w = fmaxf(mz * fmaxf(acc[i][j][3] + b4.w, 0.0f), 0.0f);
            *(float4*)(out + (size_t)row * NDIM + ncol) = o;
        }
    }
}

// ---------------------------------------------------------------------------
extern "C" void kernel_launch(void* const* d_in, const int* in_sizes, int n_in,
                              void* d_out, int out_size, void* d_ws, size_t ws_size,
                              hipStream_t stream) {
    const float* x    = (const float*)d_in[0];
    const int*   ids  = (const int*)  d_in[1];
    const float* mw   = (const float*)d_in[2];
    const float* emb  = (const float*)d_in[3];
    const float* Wt   = (const float*)d_in[4];
    const float* bt   = (const float*)d_in[5];
    const float* Wrc  = (const float*)d_in[6];
    const float* brc  = (const float*)d_in[7];
    float* out = (float*)d_out;

    char* ws = (char*)d_ws;
    unsigned short* Abf = (unsigned short*)(ws + A_OFF);
    unsigned short* Wbf = (unsigned short*)(ws + W_OFF);
    float* mwz          = (float*)(ws + MWZ_OFF);

    prep_kernel<<<2048, 256, 0, stream>>>(x, ids, mw, emb, Wrc, brc, Wt,
                                          Abf, Wbf, mwz);

    dim3 grid(MROWS / BM * (NDIM / BN));   // 32*8 = 256 blocks = 1/CU exactly
    gemm_kernel<<<grid, 512, 0, stream>>>(Abf, Wbf, bt, mwz, out);
}

// Round 2
// 208.447 us; speedup vs baseline: 1.1097x; 1.1097x over previous
//
#include <hip/hip_runtime.h>
#include <hip/hip_bf16.h>
#include <math.h>

// Problem dims (fixed by the reference): B=4096, M=2, D=2048
#define MROWS 8192   // B*M rows of the GEMM
#define KDIM  2048
#define NDIM  2048

#define BM 256
#define BN 256
#define BK 64
#define NT (KDIM / BK)   // 32 K-tiles

typedef short  v8s __attribute__((ext_vector_type(8)));   // 8 bf16 (4 VGPRs)
typedef float  v4f __attribute__((ext_vector_type(4)));   // MFMA acc

// workspace layout (bytes)
#define A_OFF   0ull
#define W_OFF   ((unsigned long long)MROWS * KDIM * 2ull)               // 32 MiB
#define MWZ_OFF (W_OFF + (unsigned long long)NDIM * KDIM * 2ull)        // +8 MiB

__device__ inline unsigned short f2bf(float f) {
    __hip_bfloat16 h = __float2bfloat16(f);   // RNE
    return *reinterpret_cast<unsigned short*>(&h);
}

// ---------------------------------------------------------------------------
// Prep: zeta scalar, A = bf16(x + emb[ids]), W = bf16(Wt)   [UNCHANGED]
// ---------------------------------------------------------------------------
__global__ __launch_bounds__(256) void prep_kernel(
    const float* __restrict__ x, const int* __restrict__ ids,
    const float* __restrict__ mw, const float* __restrict__ emb,
    const float* __restrict__ Wrc, const float* __restrict__ brc,
    const float* __restrict__ Wt,
    unsigned short* __restrict__ Abf, unsigned short* __restrict__ Wbf,
    float* __restrict__ mwz)
{
    const int tid = threadIdx.x;

    if (blockIdx.x == 0) {
        __shared__ float red[256];
        float s = 0.f;
        for (int d = tid; d < KDIM; d += 256) s += Wrc[d];
        red[tid] = s;
        __syncthreads();
        for (int off = 128; off > 0; off >>= 1) {
            if (tid < off) red[tid] += red[tid + off];
            __syncthreads();
        }
        if (tid == 0) {
            float zeta = 1.0f / (1.0f + expf(-(0.2f * red[0] + brc[0])));
            mwz[0] = mw[0] * zeta;
            mwz[1] = mw[1] * zeta;
        }
    }

    const int groupsA = MROWS * KDIM / 8;
    for (int g = blockIdx.x * 256 + tid; g < groupsA; g += gridDim.x * 256) {
        const int row = g >> 8;
        const int off = (g & 255) << 3;
        const int st  = ids[row];
        const float4* xp = (const float4*)(x   + (size_t)row * KDIM + off);
        const float4* ep = (const float4*)(emb + (size_t)st  * KDIM + off);
        float4 x0 = xp[0], x1 = xp[1];
        float4 e0 = ep[0], e1 = ep[1];
        v8s o;
        o[0] = (short)f2bf(x0.x + e0.x);
        o[1] = (short)f2bf(x0.y + e0.y);
        o[2] = (short)f2bf(x0.z + e0.z);
        o[3] = (short)f2bf(x0.w + e0.w);
        o[4] = (short)f2bf(x1.x + e1.x);
        o[5] = (short)f2bf(x1.y + e1.y);
        o[6] = (short)f2bf(x1.z + e1.z);
        o[7] = (short)f2bf(x1.w + e1.w);
        *(v8s*)(Abf + (size_t)g * 8) = o;
    }

    const int groupsW = NDIM * KDIM / 8;
    for (int g = blockIdx.x * 256 + tid; g < groupsW; g += gridDim.x * 256) {
        const float4* wp = (const float4*)(Wt + (size_t)g * 8);
        float4 w0 = wp[0], w1 = wp[1];
        v8s o;
        o[0] = (short)f2bf(w0.x); o[1] = (short)f2bf(w0.y);
        o[2] = (short)f2bf(w0.z); o[3] = (short)f2bf(w0.w);
        o[4] = (short)f2bf(w1.x); o[5] = (short)f2bf(w1.y);
        o[6] = (short)f2bf(w1.z); o[7] = (short)f2bf(w1.w);
        *(v8s*)(Wbf + (size_t)g * 8) = o;
    }
}

// ---------------------------------------------------------------------------
// GEMM v3: identical schedule to v2 (256x256, 8 waves, BK=64, dbuf LDS,
// 4-phase/K-tile, counted vmcnt, setprio, verified fetch-side XOR swizzle —
// SQ_LDS_BANK_CONFLICT measured 0), with ONE change vs v2:
//
//   BLOCK MAPPING REVERTED to the R3-proven 2D layout (br = blockIdx.x fast,
//   bc = blockIdx.y). v2's "each XCD owns one bc" permute gave ZERO cross-
//   block A-reuse within an XCD (every bc needs every A panel) -> FETCH_SIZE
//   tripled (49.2 -> 141.6 GB-units), loads went L3-latency, counted-vmcnt
//   windows (~600-750 cyc) no longer covered load latency -> MfmaUtil 26%.
//   The R3 mapping measured compulsory-only fetch (49 GB-units): blocks are
//   barrier-paced at identical rates, so co-resident blocks stay
//   K-synchronized and the live per-K-slice working set (~384 KiB/XCD) far
//   fits L2 -> panel slices fetched once, shared by all resident blocks.
//
// Region lifetimes per K-tile t (buf c = t&1), per-wave issue stream
// (2 global_load_lds calls per phase, 1 vmcnt unit each):
//   P0: read B(all)+A(rows 0-31 of wave)  | issue [t+1: A-q1,A-q3] -> c^1
//   P1: read A(rows 32-63)                | issue [t+2: B-q0,B-q1] -> c
//   P2: read A(rows 64-95)                | issue [t+2: B-q2,B-q3] -> c
//   P3: read A(rows 96-127)               | issue [t+2: A-q0,A-q2] -> c
// Waits (FIFO-counted): end-P1 vmcnt(10)  -> [t:A-q1,A-q3] landed (P2/P3 reads)
//                       end-P3 vmcnt(8)   -> [t+1: B*,A-q0,A-q2] landed (next P0/P1)
// lgkmcnt(0) before each closing barrier pins read-completion before any wave
// can issue an overwrite of that region. Tail stages wrap ((t+2)&31) into
// already-freed regions of the correct parity buffer (vmcnt counts stay exact).
// ---------------------------------------------------------------------------

#define SBAR()   __builtin_amdgcn_s_barrier()
#define LGKM0()  asm volatile("s_waitcnt lgkmcnt(0)" ::: "memory")
#define VMCNT(n) asm volatile("s_waitcnt vmcnt(" #n ")" ::: "memory")

template<int P>
__device__ __forceinline__ void mfma_phase(v4f (&acc)[8][4],
                                           const v8s (&b)[4][2],
                                           const v8s (&a)[2][2])
{
    __builtin_amdgcn_s_setprio(1);
    #pragma unroll
    for (int j = 0; j < 4; ++j) {
        acc[2*P  ][j] = __builtin_amdgcn_mfma_f32_16x16x32_bf16(b[j][0], a[0][0], acc[2*P  ][j], 0, 0, 0);
        acc[2*P+1][j] = __builtin_amdgcn_mfma_f32_16x16x32_bf16(b[j][0], a[1][0], acc[2*P+1][j], 0, 0, 0);
    }
    #pragma unroll
    for (int j = 0; j < 4; ++j) {
        acc[2*P  ][j] = __builtin_amdgcn_mfma_f32_16x16x32_bf16(b[j][1], a[0][1], acc[2*P  ][j], 0, 0, 0);
        acc[2*P+1][j] = __builtin_amdgcn_mfma_f32_16x16x32_bf16(b[j][1], a[1][1], acc[2*P+1][j], 0, 0, 0);
    }
    __builtin_amdgcn_s_setprio(0);
}

__global__ __launch_bounds__(512, 2) void gemm_kernel(
    const unsigned short* __restrict__ Abf,
    const unsigned short* __restrict__ Wbf,
    const float* __restrict__ bt,
    const float* __restrict__ mwz,
    float* __restrict__ out)
{
    __shared__ __align__(16) unsigned short lA[2][BM * BK];   // 2 x 32 KiB
    __shared__ __align__(16) unsigned short lB[2][BN * BK];   // 2 x 32 KiB

    const int tid  = threadIdx.x;
    const int lane = tid & 63;
    const int wave = tid >> 6;        // 0..7
    const int wr   = wave & 1;        // M half (128 rows)
    const int wc   = wave >> 1;       // N quarter (64 cols)
    const int quad = lane >> 4;       // 0..3
    const int mcol = lane & 15;       // 0..15

    // R3-proven mapping: br fast in blockIdx.x, bc in blockIdx.y.
    const int br = blockIdx.x;        // 32 row-blocks
    const int bc = blockIdx.y;        // 8 col-blocks

    const unsigned short* gA = Abf + (size_t)(br * BM) * KDIM;
    const unsigned short* gB = Wbf + (size_t)(bc * BN) * KDIM;

    v4f acc[8][4];
    const v4f vzero = {0.f, 0.f, 0.f, 0.f};
    #pragma unroll
    for (int i = 0; i < 8; i++)
        #pragma unroll
        for (int j = 0; j < 4; j++) acc[i][j] = vzero;

    // --- stage one 64-row quarter (8 KiB = 512 thr x 16 B) of a tile ---
    // LDS slot f holds row=f>>3, global chunk ch=(f&7)^(row&7)  (verified T2)
    auto stA = [&](int t, int s) {
        const int f   = (s << 9) + tid;
        const int row = f >> 3;
        const int ch  = (f & 7) ^ (row & 7);
        const unsigned short* g = gA + (size_t)row * KDIM + ((t & 31) << 6) + (ch << 3);
        __builtin_amdgcn_global_load_lds(
            (const __attribute__((address_space(1))) void*)g,
            (__attribute__((address_space(3))) void*)(&lA[t & 1][(size_t)f << 3]),
            16, 0, 0);
    };
    auto stB = [&](int t, int s) {
        const int f   = (s << 9) + tid;
        const int row = f >> 3;
        const int ch  = (f & 7) ^ (row & 7);
        const unsigned short* g = gB + (size_t)row * KDIM + ((t & 31) << 6) + (ch << 3);
        __builtin_amdgcn_global_load_lds(
            (const __attribute__((address_space(1))) void*)g,
            (__attribute__((address_space(3))) void*)(&lB[t & 1][(size_t)f << 3]),
            16, 0, 0);
    };

    // --- fragment reads (identical unswizzle math to verified R3 kernel) ---
    auto rdA = [&](const unsigned short* l, int i, int ks) -> v8s {
        const int row = (wr << 7) + (i << 4) + mcol;
        const int c   = ((ks << 2) + quad) ^ (row & 7);
        return *(const v8s*)(l + (row << 6) + (c << 3));
    };
    auto rdB = [&](const unsigned short* l, int j, int ks) -> v8s {
        const int col = (wc << 6) + (j << 4) + mcol;
        const int c   = ((ks << 2) + quad) ^ (col & 7);
        return *(const v8s*)(l + (col << 6) + (c << 3));
    };

    // ---- prologue: tile0 fully + tile1 {B*, A-q0,A-q2}; 14 calls in flight
    stB(0, 0); stB(0, 1); stB(0, 2); stB(0, 3);
    stA(0, 0); stA(0, 2);
    stA(0, 1); stA(0, 3);
    stB(1, 0); stB(1, 1); stB(1, 2); stB(1, 3);
    stA(1, 0); stA(1, 2);
    VMCNT(8);                 // oldest 6 = [t0: B*, A-q0,A-q2] landed
    SBAR();

    for (int t = 0; t < NT; ++t) {
        const unsigned short* cA = &lA[t & 1][0];
        const unsigned short* cB = &lB[t & 1][0];
        v8s a[2][2], b[4][2];

        // ---- P0 ----
        #pragma unroll
        for (int j = 0; j < 4; ++j) {
            b[j][0] = rdB(cB, j, 0);
            b[j][1] = rdB(cB, j, 1);
        }
        a[0][0] = rdA(cA, 0, 0); a[0][1] = rdA(cA, 0, 1);
        a[1][0] = rdA(cA, 1, 0); a[1][1] = rdA(cA, 1, 1);
        stA(t + 1, 1); stA(t + 1, 3);
        SBAR();
        mfma_phase<0>(acc, b, a);
        LGKM0(); SBAR();

        // ---- P1 ----
        a[0][0] = rdA(cA, 2, 0); a[0][1] = rdA(cA, 2, 1);
        a[1][0] = rdA(cA, 3, 0); a[1][1] = rdA(cA, 3, 1);
        stB(t + 2, 0); stB(t + 2, 1);
        SBAR();
        mfma_phase<1>(acc, b, a);
        LGKM0();
        VMCNT(10);            // [t: A-q1,A-q3] landed for P2/P3
        SBAR();

        // ---- P2 ----
        a[0][0] = rdA(cA, 4, 0); a[0][1] = rdA(cA, 4, 1);
        a[1][0] = rdA(cA, 5, 0); a[1][1] = rdA(cA, 5, 1);
        stB(t + 2, 2); stB(t + 2, 3);
        SBAR();
        mfma_phase<2>(acc, b, a);
        LGKM0(); SBAR();

        // ---- P3 ----
        a[0][0] = rdA(cA, 6, 0); a[0][1] = rdA(cA, 6, 1);
        a[1][0] = rdA(cA, 7, 0); a[1][1] = rdA(cA, 7, 1);
        stA(t + 2, 0); stA(t + 2, 2);
        SBAR();
        mfma_phase<3>(acc, b, a);
        LGKM0();
        VMCNT(8);             // [t+1: B*, A-q0,A-q2] landed for next P0/P1
        SBAR();
    }

    // ---- epilogue: bias + relu + scale + relu, dwordx4 fp32 stores ----
    // operand swap => acc holds out^T tile: reg-index = output COLUMN,
    // mcol = output ROW. Row parity = mcol & 1 (all tile offsets even).
    const float mz = mwz[mcol & 1];
    #pragma unroll
    for (int j = 0; j < 4; ++j) {
        const int ncol = bc * BN + wc * 64 + j * 16 + quad * 4;
        const float4 b4 = *(const float4*)(bt + ncol);
        #pragma unroll
        for (int i = 0; i < 8; ++i) {
            const int row = br * BM + wr * 128 + i * 16 + mcol;
            float4 o;
            o.x = fmaxf(mz * fmaxf(acc[i][j][0] + b4.x, 0.0f), 0.0f);
            o.y = fmaxf(mz * fmaxf(acc[i][j][1] + b4.y, 0.0f), 0.0f);
            o.z = fmaxf(mz * fmaxf(acc[i][j][2] + b4.z, 0.0f), 0.0f);
            o.w = fmaxf(mz * fmaxf(acc[i][j][3] + b4.w, 0.0f), 0.0f);
            *(float4*)(out + (size_t)row * NDIM + ncol) = o;
        }
    }
}

// ---------------------------------------------------------------------------
extern "C" void kernel_launch(void* const* d_in, const int* in_sizes, int n_in,
                              void* d_out, int out_size, void* d_ws, size_t ws_size,
                              hipStream_t stream) {
    const float* x    = (const float*)d_in[0];
    const int*   ids  = (const int*)  d_in[1];
    const float* mw   = (const float*)d_in[2];
    const float* emb  = (const float*)d_in[3];
    const float* Wt   = (const float*)d_in[4];
    const float* bt   = (const float*)d_in[5];
    const float* Wrc  = (const float*)d_in[6];
    const float* brc  = (const float*)d_in[7];
    float* out = (float*)d_out;

    char* ws = (char*)d_ws;
    unsigned short* Abf = (unsigned short*)(ws + A_OFF);
    unsigned short* Wbf = (unsigned short*)(ws + W_OFF);
    float* mwz          = (float*)(ws + MWZ_OFF);

    prep_kernel<<<2048, 256, 0, stream>>>(x, ids, mw, emb, Wrc, brc, Wt,
                                          Abf, Wbf, mwz);

    dim3 grid(MROWS / BM, NDIM / BN);   // 32 x 8 = 256 blocks = 1/CU exactly
    gemm_kernel<<<grid, 512, 0, stream>>>(Abf, Wbf, bt, mwz, out);
}

// Round 3
// 202.198 us; speedup vs baseline: 1.1440x; 1.0309x over previous
//
#include <hip/hip_runtime.h>
#include <hip/hip_bf16.h>
#include <math.h>

// Problem dims (fixed by the reference): B=4096, M=2, D=2048
#define MROWS 8192   // B*M rows of the GEMM
#define KDIM  2048
#define NDIM  2048

#define BM 256
#define BN 256
#define BK 64
#define NT (KDIM / BK)   // 32 K-tiles

typedef short  v8s __attribute__((ext_vector_type(8)));   // 8 bf16 (4 VGPRs)
typedef float  v4f __attribute__((ext_vector_type(4)));   // MFMA acc

// workspace layout (bytes)
#define A_OFF   0ull
#define W_OFF   ((unsigned long long)MROWS * KDIM * 2ull)               // 32 MiB
#define MWZ_OFF (W_OFF + (unsigned long long)NDIM * KDIM * 2ull)        // +8 MiB

__device__ inline unsigned short f2bf(float f) {
    __hip_bfloat16 h = __float2bfloat16(f);   // RNE
    return *reinterpret_cast<unsigned short*>(&h);
}

// ---------------------------------------------------------------------------
// Prep: zeta scalar, A = bf16(x + emb[ids]), W = bf16(Wt)   [UNCHANGED]
// ---------------------------------------------------------------------------
__global__ __launch_bounds__(256) void prep_kernel(
    const float* __restrict__ x, const int* __restrict__ ids,
    const float* __restrict__ mw, const float* __restrict__ emb,
    const float* __restrict__ Wrc, const float* __restrict__ brc,
    const float* __restrict__ Wt,
    unsigned short* __restrict__ Abf, unsigned short* __restrict__ Wbf,
    float* __restrict__ mwz)
{
    const int tid = threadIdx.x;

    if (blockIdx.x == 0) {
        __shared__ float red[256];
        float s = 0.f;
        for (int d = tid; d < KDIM; d += 256) s += Wrc[d];
        red[tid] = s;
        __syncthreads();
        for (int off = 128; off > 0; off >>= 1) {
            if (tid < off) red[tid] += red[tid + off];
            __syncthreads();
        }
        if (tid == 0) {
            float zeta = 1.0f / (1.0f + expf(-(0.2f * red[0] + brc[0])));
            mwz[0] = mw[0] * zeta;
            mwz[1] = mw[1] * zeta;
        }
    }

    const int groupsA = MROWS * KDIM / 8;
    for (int g = blockIdx.x * 256 + tid; g < groupsA; g += gridDim.x * 256) {
        const int row = g >> 8;
        const int off = (g & 255) << 3;
        const int st  = ids[row];
        const float4* xp = (const float4*)(x   + (size_t)row * KDIM + off);
        const float4* ep = (const float4*)(emb + (size_t)st  * KDIM + off);
        float4 x0 = xp[0], x1 = xp[1];
        float4 e0 = ep[0], e1 = ep[1];
        v8s o;
        o[0] = (short)f2bf(x0.x + e0.x);
        o[1] = (short)f2bf(x0.y + e0.y);
        o[2] = (short)f2bf(x0.z + e0.z);
        o[3] = (short)f2bf(x0.w + e0.w);
        o[4] = (short)f2bf(x1.x + e1.x);
        o[5] = (short)f2bf(x1.y + e1.y);
        o[6] = (short)f2bf(x1.z + e1.z);
        o[7] = (short)f2bf(x1.w + e1.w);
        *(v8s*)(Abf + (size_t)g * 8) = o;
    }

    const int groupsW = NDIM * KDIM / 8;
    for (int g = blockIdx.x * 256 + tid; g < groupsW; g += gridDim.x * 256) {
        const float4* wp = (const float4*)(Wt + (size_t)g * 8);
        float4 w0 = wp[0], w1 = wp[1];
        v8s o;
        o[0] = (short)f2bf(w0.x); o[1] = (short)f2bf(w0.y);
        o[2] = (short)f2bf(w0.z); o[3] = (short)f2bf(w0.w);
        o[4] = (short)f2bf(w1.x); o[5] = (short)f2bf(w1.y);
        o[6] = (short)f2bf(w1.z); o[7] = (short)f2bf(w1.w);
        *(v8s*)(Wbf + (size_t)g * 8) = o;
    }
}

// ---------------------------------------------------------------------------
// GEMM v4: schedule identical to v3 (256x256, 8 waves, BK=64, 4-phase/K-tile,
// counted vmcnt, setprio, R3-proven 2D block mapping — FETCH_SIZE verified
// compulsory-only at 52 GB-units, bank conflicts 0), with ONE change:
//
//   STATIC LDS DOUBLE-BUFFERING. v3 addressed both buffers through one array
//   with a runtime parity index (lA[t&1]) -> LLVM's waitcnt pass cannot
//   alias-disambiguate the in-flight global_load_lds DMA writes from the
//   ds_reads (same LDS object) and inserts its own conservative
//   s_waitcnt vmcnt(0) before every phase's LDS reads. The hand-counted
//   VMCNT(10)/VMCNT(8) don't remove compiler-inserted waits, so v3 ran as a
//   fully-drained 8-barrier/K-tile schedule at 1 block/CU: 87 us, MfmaUtil
//   31% (worse than the plain 2-barrier kernel). This is the same pathology
//   the original session hit with runtime-indexed dbuf (R4/R5 note).
//   Fix = the m201 reference structure: loop unrolled x2 over K-tile pairs,
//   FOUR separate __shared__ arrays (lA0/lA1/lB0/lB1), every stage dest and
//   ds_read source a compile-time-distinct object -> the pass can prove
//   non-aliasing and leave only the hand-placed counted waits.
//
// Region lifetimes per K-tile t (even tile shown; odd is the mirror):
//   P0: read B(all)+A(i=0,1)  | stage [t+1: A-q1,A-q3] -> other A buf
//   P1: read A(i=2,3)         | stage [t+2: B-q0,B-q1] -> SAME B buf
//   P2: read A(i=4,5)         | stage [t+2: B-q2,B-q3] -> SAME B buf
//   P3: read A(i=6,7)         | stage [t+2: A-q0,A-q2] -> SAME A buf
// Waits (FIFO-counted, 8 issues/K-tile): end-P1 VMCNT(10) -> [t: A-q1,A-q3]
// landed (P2/P3 reads); end-P3 VMCNT(8) -> [t+1: B*, A-q0,A-q2] landed (next
// P0/P1 reads). vmcnt never reaches 0 in the main loop. LGKM0 before each
// closing barrier pins this wave's ds_read completion before any wave can
// issue an overwrite of that region. Tail stages wrap ((t+2)&31) into
// already-freed regions of the correct parity buffer (counts stay exact).
// ---------------------------------------------------------------------------

#define SBAR()   __builtin_amdgcn_s_barrier()
#define LGKM0()  asm volatile("s_waitcnt lgkmcnt(0)" ::: "memory")
#define VMCNT(n) asm volatile("s_waitcnt vmcnt(" #n ")" ::: "memory")

template<int P>
__device__ __forceinline__ void mfma_phase(v4f (&acc)[8][4],
                                           const v8s (&b)[4][2],
                                           const v8s (&a)[2][2])
{
    __builtin_amdgcn_s_setprio(1);
    #pragma unroll
    for (int j = 0; j < 4; ++j) {
        acc[2*P  ][j] = __builtin_amdgcn_mfma_f32_16x16x32_bf16(b[j][0], a[0][0], acc[2*P  ][j], 0, 0, 0);
        acc[2*P+1][j] = __builtin_amdgcn_mfma_f32_16x16x32_bf16(b[j][0], a[1][0], acc[2*P+1][j], 0, 0, 0);
    }
    #pragma unroll
    for (int j = 0; j < 4; ++j) {
        acc[2*P  ][j] = __builtin_amdgcn_mfma_f32_16x16x32_bf16(b[j][1], a[0][1], acc[2*P  ][j], 0, 0, 0);
        acc[2*P+1][j] = __builtin_amdgcn_mfma_f32_16x16x32_bf16(b[j][1], a[1][1], acc[2*P+1][j], 0, 0, 0);
    }
    __builtin_amdgcn_s_setprio(0);
}

// One K-tile = 4 phases. CA/CB: buffers being computed from (and stage target
// for t+2, same parity). OA: the other A buffer (stage target for t+1).
// All three are STATIC array names at every expansion site.
#define KTILE(CA, CB, OA, T)                                              \
  {                                                                       \
    v8s a[2][2], b[4][2];                                                 \
    b[0][0] = rdB(CB, 0, 0); b[0][1] = rdB(CB, 0, 1);                     \
    b[1][0] = rdB(CB, 1, 0); b[1][1] = rdB(CB, 1, 1);                     \
    b[2][0] = rdB(CB, 2, 0); b[2][1] = rdB(CB, 2, 1);                     \
    b[3][0] = rdB(CB, 3, 0); b[3][1] = rdB(CB, 3, 1);                     \
    a[0][0] = rdA(CA, 0, 0); a[0][1] = rdA(CA, 0, 1);                     \
    a[1][0] = rdA(CA, 1, 0); a[1][1] = rdA(CA, 1, 1);                     \
    stage(OA, gA, (T) + 1, 1); stage(OA, gA, (T) + 1, 3);                 \
    SBAR(); mfma_phase<0>(acc, b, a); LGKM0(); SBAR();                    \
    a[0][0] = rdA(CA, 2, 0); a[0][1] = rdA(CA, 2, 1);                     \
    a[1][0] = rdA(CA, 3, 0); a[1][1] = rdA(CA, 3, 1);                     \
    stage(CB, gB, (T) + 2, 0); stage(CB, gB, (T) + 2, 1);                 \
    SBAR(); mfma_phase<1>(acc, b, a); LGKM0(); VMCNT(10); SBAR();         \
    a[0][0] = rdA(CA, 4, 0); a[0][1] = rdA(CA, 4, 1);                     \
    a[1][0] = rdA(CA, 5, 0); a[1][1] = rdA(CA, 5, 1);                     \
    stage(CB, gB, (T) + 2, 2); stage(CB, gB, (T) + 2, 3);                 \
    SBAR(); mfma_phase<2>(acc, b, a); LGKM0(); SBAR();                    \
    a[0][0] = rdA(CA, 6, 0); a[0][1] = rdA(CA, 6, 1);                     \
    a[1][0] = rdA(CA, 7, 0); a[1][1] = rdA(CA, 7, 1);                     \
    stage(CA, gA, (T) + 2, 0); stage(CA, gA, (T) + 2, 2);                 \
    SBAR(); mfma_phase<3>(acc, b, a); LGKM0(); VMCNT(8); SBAR();          \
  }

__global__ __launch_bounds__(512, 2) void gemm_kernel(
    const unsigned short* __restrict__ Abf,
    const unsigned short* __restrict__ Wbf,
    const float* __restrict__ bt,
    const float* __restrict__ mwz,
    float* __restrict__ out)
{
    // STATIC double-buffers: four distinct LDS objects (see header comment).
    __shared__ __align__(16) unsigned short lA0[BM * BK];   // 32 KiB
    __shared__ __align__(16) unsigned short lA1[BM * BK];   // 32 KiB
    __shared__ __align__(16) unsigned short lB0[BN * BK];   // 32 KiB
    __shared__ __align__(16) unsigned short lB1[BN * BK];   // 32 KiB

    const int tid  = threadIdx.x;
    const int lane = tid & 63;
    const int wave = tid >> 6;        // 0..7
    const int wr   = wave & 1;        // M half (128 rows)
    const int wc   = wave >> 1;       // N quarter (64 cols)
    const int quad = lane >> 4;       // 0..3
    const int mcol = lane & 15;       // 0..15

    // R3-proven mapping: br fast in blockIdx.x, bc in blockIdx.y.
    const int br = blockIdx.x;        // 32 row-blocks
    const int bc = blockIdx.y;        // 8 col-blocks

    const unsigned short* gA = Abf + (size_t)(br * BM) * KDIM;
    const unsigned short* gB = Wbf + (size_t)(bc * BN) * KDIM;

    v4f acc[8][4];
    const v4f vzero = {0.f, 0.f, 0.f, 0.f};
    #pragma unroll
    for (int i = 0; i < 8; i++)
        #pragma unroll
        for (int j = 0; j < 4; j++) acc[i][j] = vzero;

    // --- stage one 64-row quarter (8 KiB = 512 thr x 16 B) of a tile ---
    // LDS slot f holds row=f>>3, global chunk ch=(f&7)^(row&7)  (verified T2)
    auto stage = [&](unsigned short* dst, const unsigned short* gsrc,
                     int t, int s) {
        const int f   = (s << 9) + tid;
        const int row = f >> 3;
        const int ch  = (f & 7) ^ (row & 7);
        const unsigned short* g = gsrc + (size_t)row * KDIM + ((t & 31) << 6) + (ch << 3);
        __builtin_amdgcn_global_load_lds(
            (const __attribute__((address_space(1))) void*)g,
            (__attribute__((address_space(3))) void*)(dst + ((size_t)f << 3)),
            16, 0, 0);
    };

    // --- fragment reads (identical unswizzle math to verified R3 kernel) ---
    auto rdA = [&](const unsigned short* l, int i, int ks) -> v8s {
        const int row = (wr << 7) + (i << 4) + mcol;
        const int c   = ((ks << 2) + quad) ^ (row & 7);
        return *(const v8s*)(l + (row << 6) + (c << 3));
    };
    auto rdB = [&](const unsigned short* l, int j, int ks) -> v8s {
        const int col = (wc << 6) + (j << 4) + mcol;
        const int c   = ((ks << 2) + quad) ^ (col & 7);
        return *(const v8s*)(l + (col << 6) + (c << 3));
    };

    // ---- prologue: tile0 fully + tile1 {B*, A-q0,A-q2}; 14 calls in flight
    stage(lB0, gB, 0, 0); stage(lB0, gB, 0, 1);
    stage(lB0, gB, 0, 2); stage(lB0, gB, 0, 3);
    stage(lA0, gA, 0, 0); stage(lA0, gA, 0, 2);
    stage(lA0, gA, 0, 1); stage(lA0, gA, 0, 3);
    stage(lB1, gB, 1, 0); stage(lB1, gB, 1, 1);
    stage(lB1, gB, 1, 2); stage(lB1, gB, 1, 3);
    stage(lA1, gA, 1, 0); stage(lA1, gA, 1, 2);
    VMCNT(8);                 // oldest 6 = [t0: B*, A-q0,A-q2] landed
    SBAR();

    #pragma unroll 1
    for (int tt = 0; tt < NT; tt += 2) {
        KTILE(lA0, lB0, lA1, tt);       // even tile: bufs 0
        KTILE(lA1, lB1, lA0, tt + 1);   // odd tile:  bufs 1
    }

    // ---- epilogue: bias + relu + scale + relu, dwordx4 fp32 stores ----
    // operand swap => acc holds out^T tile: reg-index = output COLUMN,
    // mcol = output ROW. Row parity = mcol & 1 (all tile offsets even).
    const float mz = mwz[mcol & 1];
    #pragma unroll
    for (int j = 0; j < 4; ++j) {
        const int ncol = bc * BN + wc * 64 + j * 16 + quad * 4;
        const float4 b4 = *(const float4*)(bt + ncol);
        #pragma unroll
        for (int i = 0; i < 8; ++i) {
            const int row = br * BM + wr * 128 + i * 16 + mcol;
            float4 o;
            o.x = fmaxf(mz * fmaxf(acc[i][j][0] + b4.x, 0.0f), 0.0f);
            o.y = fmaxf(mz * fmaxf(acc[i][j][1] + b4.y, 0.0f), 0.0f);
            o.z = fmaxf(mz * fmaxf(acc[i][j][2] + b4.z, 0.0f), 0.0f);
            o.w = fmaxf(mz * fmaxf(acc[i][j][3] + b4.w, 0.0f), 0.0f);
            *(float4*)(out + (size_t)row * NDIM + ncol) = o;
        }
    }
}

// ---------------------------------------------------------------------------
extern "C" void kernel_launch(void* const* d_in, const int* in_sizes, int n_in,
                              void* d_out, int out_size, void* d_ws, size_t ws_size,
                              hipStream_t stream) {
    const float* x    = (const float*)d_in[0];
    const int*   ids  = (const int*)  d_in[1];
    const float* mw   = (const float*)d_in[2];
    const float* emb  = (const float*)d_in[3];
    const float* Wt   = (const float*)d_in[4];
    const float* bt   = (const float*)d_in[5];
    const float* Wrc  = (const float*)d_in[6];
    const float* brc  = (const float*)d_in[7];
    float* out = (float*)d_out;

    char* ws = (char*)d_ws;
    unsigned short* Abf = (unsigned short*)(ws + A_OFF);
    unsigned short* Wbf = (unsigned short*)(ws + W_OFF);
    float* mwz          = (float*)(ws + MWZ_OFF);

    prep_kernel<<<2048, 256, 0, stream>>>(x, ids, mw, emb, Wrc, brc, Wt,
                                          Abf, Wbf, mwz);

    dim3 grid(MROWS / BM, NDIM / BN);   // 32 x 8 = 256 blocks = 1/CU exactly
    gemm_kernel<<<grid, 512, 0, stream>>>(Abf, Wbf, bt, mwz, out);
}